// Round 15
// baseline (639.867 us; speedup 1.0000x reference)
//
#include <hip/hip_runtime.h>
#include <math.h>

// B=4096, S=64, H=256, 2 GRU layers.
// 32 clusters x 8 WGs (=256 WGs, 1/CU forced by 157KB LDS). Weight slice
// (144 KB fp16) LDS-resident. BASE: R14 (best verified, 628 us) — two-phase
// flag split + A0 prefetch, wave-private 16 rows x 32 cols, zero-
// __syncthreads barrier, coalesced coop-stores, batched IC-coherent loads.
// THIS ROUND (single change): DEFER ARRIVE0. Phase 0 issues the h0n store
// but does NOT drain it; POLL(1,i-1)'s internal vmcnt(0) absorbs the
// store-ack for free, then ARRIVE(0,i) runs with vmcnt already 0 (LDS inc
// + flag byte only). Removes the ~0.5-0.8us serial store-drain from the
// per-step chain. Deadlock audit: ARRIVE(0,i) <- flag1(i-1) <- step-(i-1)
// work only; POLL(0,i) (A0-prefetch gate) sits at end of phase 1 -> no cycle.
#define NCL 32
#define CW  8
#define BTC 128
#define NT  512
#define SS  64
#define HH  256

typedef __attribute__((ext_vector_type(8))) _Float16 half8;
typedef __attribute__((ext_vector_type(4))) float    f32x4;

__device__ __forceinline__ float sigmoidf_(float v){
    return __builtin_amdgcn_rcpf(1.f + __expf(-v));
}
__device__ __forceinline__ float tanhf_(float x){
    return 1.f - 2.f*__builtin_amdgcn_rcpf(1.f + __expf(2.f*x));
}

// 16B cache-bypassing load (served at the IC coherence point). Result NOT
// ready until a subsequent s_waitcnt vmcnt(N) that pins the dest regs.
__device__ __forceinline__ half8 ldA16(const _Float16* p){
    half8 r;
    asm volatile("global_load_dwordx4 %0, %1, off sc0 sc1" : "=v"(r) : "v"(p));
    return r;
}
// 2B write-through to IC (interval-0 only)
__device__ __forceinline__ void stH(_Float16* p, float v){
    _Float16 hv = (_Float16)v;
    asm volatile("global_store_short %0, %1, off sc0 sc1" :: "v"(p), "v"(hv));
}
// 16B write-through to IC (coalesced coop store)
__device__ __forceinline__ void stH16(_Float16* p, half8 v){
    asm volatile("global_store_dwordx4 %0, %1, off sc0 sc1" :: "v"(p), "v"(v));
}

// LDS weight layout: halfs offset = mat*24576 + ntl*4096 + kt*512 + lane*8
// mat: 0=Whh0 1=Wih1 2=Whh1 ; ntl = type*2 + h2 (type 0=r,1=z,2=n)
#define WOFF(mat,ntl,kt) ((mat)*24576 + (ntl)*4096 + (kt)*512)

__global__ void zero_flags(int* f){
    int i = blockIdx.x*blockDim.x + threadIdx.x;
    if (i < NCL*SS*4) f[i] = 0;
}

// counted wait + pin 8 A-regs + scheduling fence
#define WAIT_PIN8(NSTR, A)                                                    \
    asm volatile("s_waitcnt vmcnt(" NSTR ")"                                  \
      : "+v"(A[0]),"+v"(A[1]),"+v"(A[2]),"+v"(A[3]),                          \
        "+v"(A[4]),"+v"(A[5]),"+v"(A[6]),"+v"(A[7]) :: "memory");             \
    __builtin_amdgcn_sched_barrier(0)

// per-wave arrival for phase PH: drain own VM ops, LDS count to 8,
// last wave stores the WG's flag byte for (step, phase)
#define ARRIVE(PH, IDX)                                                       \
    asm volatile("s_waitcnt vmcnt(0)" ::: "memory");                          \
    if (L == 0){                                                              \
        int old = __hip_atomic_fetch_add(&cntL[PH][(IDX)], 1, __ATOMIC_ACQ_REL,\
                                         __HIP_MEMORY_SCOPE_WORKGROUP);       \
        if (old == 7){ unsigned int one = 1;                                  \
            asm volatile("global_store_byte %0, %1, off sc0 sc1"              \
                :: "v"(flg8 + ((IDX)*2+(PH))*8 + j), "v"(one) : "memory"); }  \
    }

// per-wave poll: 8 WG-bytes of (step IDX, phase PH) must all be 1
#define POLL(PH, IDX)                                                         \
    {                                                                         \
        const unsigned char* fp = flg8 + ((IDX)*2+(PH))*8;                    \
        int guard = 0;                                                        \
        for (;;){                                                             \
            unsigned long long v;                                             \
            asm volatile("global_load_dwordx2 %0, %1, off sc0 sc1\n\t"        \
                         "s_waitcnt vmcnt(0)"                                 \
                         : "=v"(v) : "v"(fp) : "memory");                     \
            if (v == 0x0101010101010101ULL) break;                            \
            __builtin_amdgcn_s_sleep(1);                                      \
            if (++guard > (1<<20)) break;   /* never hang the harness */      \
        }                                                                     \
    }

__global__ __launch_bounds__(NT,2) void rnn_cluster(
    const int*   __restrict__ x,
    const float* __restrict__ Wih0,
    const float* __restrict__ Whh0,
    const float* __restrict__ Wih1,
    const float* __restrict__ Whh1,
    const float* __restrict__ Wl,
    const float* __restrict__ bl,
    float*       __restrict__ out,
    int*         __restrict__ flags,  // (NCL, SS, 2 phases, 8 bytes)
    _Float16*    __restrict__ Hbuf)   // 2 layers x NCL x 2 bufs x 128x256 halfs
{
    __shared__ _Float16 wlds[3*6*8*64*8];          // 147456 B
    __shared__ _Float16 hstage[8*512];             // 8 KB: 1 KB per wave
    __shared__ unsigned long long bitsM[BTC];      // 1 KB
    __shared__ int cntL[2][SS];

    const int t   = threadIdx.x;
    const int c   = blockIdx.x & (NCL-1);
    const int j   = blockIdx.x >> 5;               // member 0..7
    const int L   = t & 63;
    const int w   = t >> 6;
    const int lm  = L & 15, quad = L >> 4;
    const int rw  = 16*w;                          // this wave's row base

    _Float16* H0 = Hbuf + (size_t)c*(2*BTC*HH);
    _Float16* H1 = Hbuf + (size_t)(NCL + c)*(2*BTC*HH);
    unsigned char* flg8 = (unsigned char*)flags + (size_t)c*(SS*16);
    _Float16* stg = hstage + w*512;                // wave-private staging

    // coop-store geometry (wave-private): lane L -> row L>>2, 16B chunk L&3
    const int r2 = L >> 2, q2 = L & 3;

    // ---- one-time init ----
    { int* pc = &cntL[0][0];
      for (int k=t; k<2*SS; k+=NT) pc[k]=0; }
    for (int idx = t; idx < 3*6*8*64; idx += NT){
        int lane = idx & 63;
        int kt   = (idx >> 6) & 7;
        int ntl  = (idx >> 9) % 6;
        int mat  = idx / 3072;
        const float* W = (mat==0) ? Whh0 : (mat==1) ? Wih1 : Whh1;
        int g  = (ntl>>1)*HH + j*32 + (ntl&1)*16 + (lane & 15);
        int kb = kt*32 + (lane>>4)*8;
        _Float16* d = wlds + (size_t)idx*8;
        #pragma unroll
        for (int e=0;e<8;++e) d[e] = (_Float16)W[g*HH + kb + e];
    }
    if (t < BTC){
        unsigned long long m = 0;
        const int* xr = x + (size_t)(c*BTC + t)*SS;
        for (int s=0;s<SS;++s) if (xr[s] > 0) m |= (1ull<<s);
        bitsM[t] = m;
    }

    // layer-0 input weights for this lane's 2 owned unit columns
    float g0w[2][6];
    #pragma unroll
    for (int h2=0;h2<2;++h2){
        int ug = j*32 + h2*16 + lm;
        g0w[h2][0]=Wih0[ug*2+0];        g0w[h2][1]=Wih0[ug*2+1];
        g0w[h2][2]=Wih0[(ug+HH)*2+0];   g0w[h2][3]=Wih0[(ug+HH)*2+1];
        g0w[h2][4]=Wih0[(ug+2*HH)*2+0]; g0w[h2][5]=Wih0[(ug+2*HH)*2+1];
    }

    const int srow = j*16 + (t>>5);
    const int cs   = t & 31;
    float wl0[8], wl1[8];
    #pragma unroll
    for (int e=0;e<8;++e){ wl0[e]=Wl[cs*8+e]; wl1[e]=Wl[HH+cs*8+e]; }
    const float bl0=bl[0], bl1=bl[1];

    float hr0[2][4] = {}, hr1[2][4] = {};   // [h2][reg]
    float amp=1.f, ph=0.f, nup=0.f, ndn=0.f;

    __syncthreads();   // weights/bitsM/cntL ready (one-time)

    // ---- interval 0: h1n(0)=0; h0n(1)=GRU(x(bit0),0) ----
    #pragma unroll
    for (int h2=0;h2<2;++h2){
        #pragma unroll
        for (int reg=0;reg<4;++reg){
            int rowL = rw + 4*quad + reg;
            int ucol = j*32 + h2*16 + lm;
            stH(H1 + rowL*HH + ucol, 0.f);
            int bit = (int)(bitsM[rowL] & 1ull);
            float gr = bit?g0w[h2][1]:g0w[h2][0];
            float gz = bit?g0w[h2][3]:g0w[h2][2];
            float gn = bit?g0w[h2][5]:g0w[h2][4];
            float r = sigmoidf_(gr);
            float z = sigmoidf_(gz);
            float n = tanhf_(gn);
            float hnew = (1.f-z)*n;
            hr0[h2][reg] = hnew;
            stH(H0 + (BTC*HH) + rowL*HH + ucol, hnew);
        }
    }
    ARRIVE(0, 0)
    ARRIVE(1, 0)

    // ---- prologue prefetch: A0 for step i=1 (h0n(1) in H0 buffer 1) ----
    half8 A0[8];
    POLL(0, 0)
    {
        const _Float16* Hs0p = H0 + (BTC*HH) + (rw + lm)*HH;
        #pragma unroll
        for (int kt=0;kt<8;++kt) A0[kt] = ldA16(Hs0p + kt*32 + quad*8);
    }

    for (int i=1;i<SS;++i){
        // ================= phase 0: layer-0 recurrence (critical cycle) ====
        WAIT_PIN8("0", A0);   // prefetched at end of previous step (free)

        if (i < SS-1){
            f32x4 a0n[3][2] = {};                   // [type][h2]
            #pragma unroll
            for (int kt=0;kt<8;++kt){
                #pragma unroll
                for (int h2=0;h2<2;++h2){
                    half8 b0r = *(const half8*)(wlds + WOFF(0, 0+h2, kt) + L*8);
                    half8 b0z = *(const half8*)(wlds + WOFF(0, 2+h2, kt) + L*8);
                    half8 b0n = *(const half8*)(wlds + WOFF(0, 4+h2, kt) + L*8);
                    a0n[0][h2] = __builtin_amdgcn_mfma_f32_16x16x32_f16(A0[kt], b0r, a0n[0][h2],0,0,0);
                    a0n[1][h2] = __builtin_amdgcn_mfma_f32_16x16x32_f16(A0[kt], b0z, a0n[1][h2],0,0,0);
                    a0n[2][h2] = __builtin_amdgcn_mfma_f32_16x16x32_f16(A0[kt], b0n, a0n[2][h2],0,0,0);
                }
            }
            // ew0 -> wave-private stage
            #pragma unroll
            for (int h2=0;h2<2;++h2){
                #pragma unroll
                for (int reg=0;reg<4;++reg){
                    int rowL = rw + 4*quad + reg;
                    int bit = (int)((bitsM[rowL] >> i) & 1ull);
                    float gr = bit?g0w[h2][1]:g0w[h2][0];
                    float gz = bit?g0w[h2][3]:g0w[h2][2];
                    float gn = bit?g0w[h2][5]:g0w[h2][4];
                    float r = sigmoidf_(gr + a0n[0][h2][reg]);
                    float z = sigmoidf_(gz + a0n[1][h2][reg]);
                    float n = tanhf_(gn + r*a0n[2][h2][reg]);
                    float hnew = (1.f-z)*n + z*hr0[h2][reg];
                    hr0[h2][reg] = hnew;
                    stg[(4*quad+reg)*32 + h2*16 + lm] = (_Float16)hnew;
                }
            }
            asm volatile("s_waitcnt lgkmcnt(0)" ::: "memory");
            __builtin_amdgcn_sched_barrier(0);
            half8 v = *(const half8*)(stg + r2*32 + q2*8);
            asm volatile("s_waitcnt lgkmcnt(0)" : "+v"(v) :: "memory");
            __builtin_amdgcn_sched_barrier(0);
            stH16(H0 + ((i+1)&1)*(BTC*HH) + (rw + r2)*HH + j*32 + q2*8, v);
            // NOTE: no ARRIVE here — store drains inside POLL(1,i-1) below.
        }

        // ================= phase 1: layer-1 + sampling (one step of slack) ==
        POLL(1, i-1)          // internal vmcnt(0) absorbs the h0n store-ack
        if (i < SS-1){
            ARRIVE(0, i)      // vmcnt already 0 -> just LDS inc + flag byte
        }
        const int s = i-1;
        half8 hvv = ldA16(H1 + (s&1)*(BTC*HH) + srow*HH + cs*8);
        const _Float16* Hs1 = H1 + (s&1)*(BTC*HH) + (rw + lm)*HH;
        half8 A1[8];
        #pragma unroll
        for (int kt=0;kt<8;++kt) A1[kt] = ldA16(Hs1 + kt*32 + quad*8);

        // sampling math under A1 latency (possible older flag-byte store is
        // drained first by vmcnt(8): queue = [flag?, hvv, A1 x8])
        asm volatile("s_waitcnt vmcnt(8)" : "+v"(hvv) :: "memory");
        __builtin_amdgcn_sched_barrier(0);
        {
            float s0=0.f, s1=0.f;
            #pragma unroll
            for (int e=0;e<8;++e){ float f=(float)hvv[e]; s0+=f*wl0[e]; s1+=f*wl1[e]; }
            #pragma unroll
            for (int off=16; off>0; off>>=1){ s0+=__shfl_xor(s0,off,32); s1+=__shfl_xor(s1,off,32); }
            float l0=s0+bl0, l1=s1+bl1;
            bool  ev  = (s & 1) == 0;
            float low = -16.f + (float)(s>>1);
            float cnt = ev ? nup : ndn;
            float mocc = (16.f > cnt) ? 1.f : 0.f;
            float mun  = (low  < cnt) ? 1.f : 0.f;
            float mx = fmaxf(l0,l1);
            float e0 = __expf(l0-mx), e1 = __expf(l1-mx);
            float inv = __builtin_amdgcn_rcpf(e0+e1);
            float a0s = __builtin_amdgcn_sqrtf(e0*inv)*mun;
            float a1s = __builtin_amdgcn_sqrtf(e1*inv)*mocc;
            float nrm = __builtin_amdgcn_sqrtf(a0s*a0s + a1s*a1s);
            float den = fmaxf(nrm, 1e-12f);
            float rden = __builtin_amdgcn_rcpf(den);
            a0s*=rden; a1s*=rden;
            const float PI_F = 3.14159265358979323846f;
            float p0 = PI_F*l0*__builtin_amdgcn_rcpf(1.f+fabsf(l0));
            float p1 = PI_F*l1*__builtin_amdgcn_rcpf(1.f+fabsf(l1));
            int bit = (int)((bitsM[srow] >> s) & 1ull);
            amp *= bit ? a1s : a0s;
            ph  += bit ? p1 : p0;
            if (ev) nup += (float)bit; else ndn += (float)bit;
        }

        WAIT_PIN8("0", A1);
        f32x4 aR[2]={}, aZ[2]={}, aNI[2]={}, aNH[2]={};
        #pragma unroll
        for (int kt=0;kt<8;++kt){
            #pragma unroll
            for (int h2=0;h2<2;++h2){
                half8 b1r = *(const half8*)(wlds + WOFF(1, 0+h2, kt) + L*8);
                half8 b1z = *(const half8*)(wlds + WOFF(1, 2+h2, kt) + L*8);
                half8 b1n = *(const half8*)(wlds + WOFF(1, 4+h2, kt) + L*8);
                half8 b2r = *(const half8*)(wlds + WOFF(2, 0+h2, kt) + L*8);
                half8 b2z = *(const half8*)(wlds + WOFF(2, 2+h2, kt) + L*8);
                half8 b2n = *(const half8*)(wlds + WOFF(2, 4+h2, kt) + L*8);
                aR [h2] = __builtin_amdgcn_mfma_f32_16x16x32_f16(A0[kt], b1r, aR [h2],0,0,0);
                aZ [h2] = __builtin_amdgcn_mfma_f32_16x16x32_f16(A0[kt], b1z, aZ [h2],0,0,0);
                aNI[h2] = __builtin_amdgcn_mfma_f32_16x16x32_f16(A0[kt], b1n, aNI[h2],0,0,0);
                aR [h2] = __builtin_amdgcn_mfma_f32_16x16x32_f16(A1[kt], b2r, aR [h2],0,0,0);
                aZ [h2] = __builtin_amdgcn_mfma_f32_16x16x32_f16(A1[kt], b2z, aZ [h2],0,0,0);
                aNH[h2] = __builtin_amdgcn_mfma_f32_16x16x32_f16(A1[kt], b2n, aNH[h2],0,0,0);
            }
        }

        // ew1 -> wave-private stage -> coalesced store
        #pragma unroll
        for (int h2=0;h2<2;++h2){
            #pragma unroll
            for (int reg=0;reg<4;++reg){
                float r = sigmoidf_(aR[h2][reg]);
                float z = sigmoidf_(aZ[h2][reg]);
                float n = tanhf_(aNI[h2][reg] + r*aNH[h2][reg]);
                float hnew = (1.f-z)*n + z*hr1[h2][reg];
                hr1[h2][reg] = hnew;
                stg[(4*quad+reg)*32 + h2*16 + lm] = (_Float16)hnew;
            }
        }
        asm volatile("s_waitcnt lgkmcnt(0)" ::: "memory");
        __builtin_amdgcn_sched_barrier(0);
        {
            half8 v = *(const half8*)(stg + r2*32 + q2*8);
            asm volatile("s_waitcnt lgkmcnt(0)" : "+v"(v) :: "memory");
            __builtin_amdgcn_sched_barrier(0);
            stH16(H1 + (i&1)*(BTC*HH) + (rw + r2)*HH + j*32 + q2*8, v);
        }

        // ---- A0 prefetch for step i+1 (flag0(i) set in steady state) ----
        if (i < SS-1){
            POLL(0, i)
            const _Float16* Hs0n = H0 + ((i+1)&1)*(BTC*HH) + (rw + lm)*HH;
            #pragma unroll
            for (int kt=0;kt<8;++kt) A0[kt] = ldA16(Hs0n + kt*32 + quad*8);
        }

        ARRIVE(1, i)   // drains h1n store + prefetched A0 loads together
    }

    // ---- epilogue: wait flag1(63), sampling(63) ----
    POLL(1, SS-1)
    {
        const int s = SS-1;
        half8 hvv = ldA16(H1 + (s&1)*(BTC*HH) + srow*HH + cs*8);
        asm volatile("s_waitcnt vmcnt(0)" : "+v"(hvv) :: "memory");
        __builtin_amdgcn_sched_barrier(0);
        float s0=0.f, s1=0.f;
        #pragma unroll
        for (int e=0;e<8;++e){ float f=(float)hvv[e]; s0+=f*wl0[e]; s1+=f*wl1[e]; }
        #pragma unroll
        for (int off=16; off>0; off>>=1){ s0+=__shfl_xor(s0,off,32); s1+=__shfl_xor(s1,off,32); }
        float l0=s0+bl0, l1=s1+bl1;
        bool  ev  = (s & 1) == 0;
        float low = -16.f + (float)(s>>1);
        float cnt = ev ? nup : ndn;
        float mocc = (16.f > cnt) ? 1.f : 0.f;
        float mun  = (low  < cnt) ? 1.f : 0.f;
        float mx = fmaxf(l0,l1);
        float e0 = __expf(l0-mx), e1 = __expf(l1-mx);
        float inv = __builtin_amdgcn_rcpf(e0+e1);
        float a0s = __builtin_amdgcn_sqrtf(e0*inv)*mun;
        float a1s = __builtin_amdgcn_sqrtf(e1*inv)*mocc;
        float nrm = __builtin_amdgcn_sqrtf(a0s*a0s + a1s*a1s);
        float den = fmaxf(nrm, 1e-12f);
        float rden = __builtin_amdgcn_rcpf(den);
        a0s*=rden; a1s*=rden;
        const float PI_F = 3.14159265358979323846f;
        float p0 = PI_F*l0*__builtin_amdgcn_rcpf(1.f+fabsf(l0));
        float p1 = PI_F*l1*__builtin_amdgcn_rcpf(1.f+fabsf(l1));
        int bit = (int)((bitsM[srow] >> s) & 1ull);
        amp *= bit ? a1s : a0s;
        ph  += bit ? p1 : p0;
    }
    if (cs == 0) out[c*BTC + srow] = amp * cosf(ph);
}

extern "C" void kernel_launch(void* const* d_in, const int* in_sizes, int n_in,
                              void* d_out, int out_size, void* d_ws, size_t ws_size,
                              hipStream_t stream) {
    (void)in_sizes; (void)n_in; (void)out_size; (void)ws_size;
    const int*   x    = (const int*)d_in[0];
    const float* Wih0 = (const float*)d_in[1];
    const float* Whh0 = (const float*)d_in[2];
    const float* Wih1 = (const float*)d_in[3];
    const float* Whh1 = (const float*)d_in[4];
    const float* Wl   = (const float*)d_in[5];
    const float* bl   = (const float*)d_in[6];

    int*      flags = (int*)d_ws;                          // 32 KB (NCL*SS*2*8 bytes)
    _Float16* Hbuf  = (_Float16*)((char*)d_ws + 131072);   // 8 MB h state

    zero_flags<<<(NCL*SS*4 + 255)/256, 256, 0, stream>>>(flags);
    rnn_cluster<<<NCL*CW, NT, 0, stream>>>(x, Wih0, Whh0, Wih1, Whh1, Wl, bl,
                                           (float*)d_out, flags, Hbuf);
}

// Round 16
// 601.043 us; speedup vs baseline: 1.0646x; 1.0646x over previous
//
#include <hip/hip_runtime.h>
#include <math.h>

// B=4096, S=64, H=256, 2 GRU layers.
// 32 clusters x 8 WGs (=256 WGs, 1/CU forced by 157KB LDS). Weight slice
// (144 KB fp16) LDS-resident. BASE: R14 (best verified, 628 us) — two-phase
// flag split + A0 prefetch, wave-private 16 rows x 32 cols, zero-
// __syncthreads barrier, coalesced coop-stores, batched IC-coherent loads.
// THIS ROUND (single change): EARLY PHASE-1 HEAD. POLL(1,i-1) + hvv/A1 load
// issue are hoisted between GEMM0's MFMAs and ew0, so the A1/hvv IC round
// trips hide under ew0+staging+store; ARRIVE(0,i)'s vmcnt(0) drains them for
// free. (R15's defer-ARRIVE0 regressed and is reverted.)
#define NCL 32
#define CW  8
#define BTC 128
#define NT  512
#define SS  64
#define HH  256

typedef __attribute__((ext_vector_type(8))) _Float16 half8;
typedef __attribute__((ext_vector_type(4))) float    f32x4;

__device__ __forceinline__ float sigmoidf_(float v){
    return __builtin_amdgcn_rcpf(1.f + __expf(-v));
}
__device__ __forceinline__ float tanhf_(float x){
    return 1.f - 2.f*__builtin_amdgcn_rcpf(1.f + __expf(2.f*x));
}

// 16B cache-bypassing load (served at the IC coherence point). Result NOT
// ready until a subsequent s_waitcnt vmcnt(N) that pins the dest regs.
__device__ __forceinline__ half8 ldA16(const _Float16* p){
    half8 r;
    asm volatile("global_load_dwordx4 %0, %1, off sc0 sc1" : "=v"(r) : "v"(p));
    return r;
}
// 2B write-through to IC (interval-0 only)
__device__ __forceinline__ void stH(_Float16* p, float v){
    _Float16 hv = (_Float16)v;
    asm volatile("global_store_short %0, %1, off sc0 sc1" :: "v"(p), "v"(hv));
}
// 16B write-through to IC (coalesced coop store)
__device__ __forceinline__ void stH16(_Float16* p, half8 v){
    asm volatile("global_store_dwordx4 %0, %1, off sc0 sc1" :: "v"(p), "v"(v));
}

// LDS weight layout: halfs offset = mat*24576 + ntl*4096 + kt*512 + lane*8
// mat: 0=Whh0 1=Wih1 2=Whh1 ; ntl = type*2 + h2 (type 0=r,1=z,2=n)
#define WOFF(mat,ntl,kt) ((mat)*24576 + (ntl)*4096 + (kt)*512)

__global__ void zero_flags(int* f){
    int i = blockIdx.x*blockDim.x + threadIdx.x;
    if (i < NCL*SS*4) f[i] = 0;
}

// counted wait + pin 8 A-regs + scheduling fence
#define WAIT_PIN8(NSTR, A)                                                    \
    asm volatile("s_waitcnt vmcnt(" NSTR ")"                                  \
      : "+v"(A[0]),"+v"(A[1]),"+v"(A[2]),"+v"(A[3]),                          \
        "+v"(A[4]),"+v"(A[5]),"+v"(A[6]),"+v"(A[7]) :: "memory");             \
    __builtin_amdgcn_sched_barrier(0)

// per-wave arrival for phase PH: drain own VM ops, LDS count to 8,
// last wave stores the WG's flag byte for (step, phase)
#define ARRIVE(PH, IDX)                                                       \
    asm volatile("s_waitcnt vmcnt(0)" ::: "memory");                          \
    if (L == 0){                                                              \
        int old = __hip_atomic_fetch_add(&cntL[PH][(IDX)], 1, __ATOMIC_ACQ_REL,\
                                         __HIP_MEMORY_SCOPE_WORKGROUP);       \
        if (old == 7){ unsigned int one = 1;                                  \
            asm volatile("global_store_byte %0, %1, off sc0 sc1"              \
                :: "v"(flg8 + ((IDX)*2+(PH))*8 + j), "v"(one) : "memory"); }  \
    }

// per-wave poll: 8 WG-bytes of (step IDX, phase PH) must all be 1
#define POLL(PH, IDX)                                                         \
    {                                                                         \
        const unsigned char* fp = flg8 + ((IDX)*2+(PH))*8;                    \
        int guard = 0;                                                        \
        for (;;){                                                             \
            unsigned long long v;                                             \
            asm volatile("global_load_dwordx2 %0, %1, off sc0 sc1\n\t"        \
                         "s_waitcnt vmcnt(0)"                                 \
                         : "=v"(v) : "v"(fp) : "memory");                     \
            if (v == 0x0101010101010101ULL) break;                            \
            __builtin_amdgcn_s_sleep(1);                                      \
            if (++guard > (1<<20)) break;   /* never hang the harness */      \
        }                                                                     \
    }

__global__ __launch_bounds__(NT,2) void rnn_cluster(
    const int*   __restrict__ x,
    const float* __restrict__ Wih0,
    const float* __restrict__ Whh0,
    const float* __restrict__ Wih1,
    const float* __restrict__ Whh1,
    const float* __restrict__ Wl,
    const float* __restrict__ bl,
    float*       __restrict__ out,
    int*         __restrict__ flags,  // (NCL, SS, 2 phases, 8 bytes)
    _Float16*    __restrict__ Hbuf)   // 2 layers x NCL x 2 bufs x 128x256 halfs
{
    __shared__ _Float16 wlds[3*6*8*64*8];          // 147456 B
    __shared__ _Float16 hstage[8*512];             // 8 KB: 1 KB per wave
    __shared__ unsigned long long bitsM[BTC];      // 1 KB
    __shared__ int cntL[2][SS];

    const int t   = threadIdx.x;
    const int c   = blockIdx.x & (NCL-1);
    const int j   = blockIdx.x >> 5;               // member 0..7
    const int L   = t & 63;
    const int w   = t >> 6;
    const int lm  = L & 15, quad = L >> 4;
    const int rw  = 16*w;                          // this wave's row base

    _Float16* H0 = Hbuf + (size_t)c*(2*BTC*HH);
    _Float16* H1 = Hbuf + (size_t)(NCL + c)*(2*BTC*HH);
    unsigned char* flg8 = (unsigned char*)flags + (size_t)c*(SS*16);
    _Float16* stg = hstage + w*512;                // wave-private staging

    // coop-store geometry (wave-private): lane L -> row L>>2, 16B chunk L&3
    const int r2 = L >> 2, q2 = L & 3;

    // ---- one-time init ----
    { int* pc = &cntL[0][0];
      for (int k=t; k<2*SS; k+=NT) pc[k]=0; }
    for (int idx = t; idx < 3*6*8*64; idx += NT){
        int lane = idx & 63;
        int kt   = (idx >> 6) & 7;
        int ntl  = (idx >> 9) % 6;
        int mat  = idx / 3072;
        const float* W = (mat==0) ? Whh0 : (mat==1) ? Wih1 : Whh1;
        int g  = (ntl>>1)*HH + j*32 + (ntl&1)*16 + (lane & 15);
        int kb = kt*32 + (lane>>4)*8;
        _Float16* d = wlds + (size_t)idx*8;
        #pragma unroll
        for (int e=0;e<8;++e) d[e] = (_Float16)W[g*HH + kb + e];
    }
    if (t < BTC){
        unsigned long long m = 0;
        const int* xr = x + (size_t)(c*BTC + t)*SS;
        for (int s=0;s<SS;++s) if (xr[s] > 0) m |= (1ull<<s);
        bitsM[t] = m;
    }

    // layer-0 input weights for this lane's 2 owned unit columns
    float g0w[2][6];
    #pragma unroll
    for (int h2=0;h2<2;++h2){
        int ug = j*32 + h2*16 + lm;
        g0w[h2][0]=Wih0[ug*2+0];        g0w[h2][1]=Wih0[ug*2+1];
        g0w[h2][2]=Wih0[(ug+HH)*2+0];   g0w[h2][3]=Wih0[(ug+HH)*2+1];
        g0w[h2][4]=Wih0[(ug+2*HH)*2+0]; g0w[h2][5]=Wih0[(ug+2*HH)*2+1];
    }

    const int srow = j*16 + (t>>5);
    const int cs   = t & 31;
    float wl0[8], wl1[8];
    #pragma unroll
    for (int e=0;e<8;++e){ wl0[e]=Wl[cs*8+e]; wl1[e]=Wl[HH+cs*8+e]; }
    const float bl0=bl[0], bl1=bl[1];

    float hr0[2][4] = {}, hr1[2][4] = {};   // [h2][reg]
    float amp=1.f, ph=0.f, nup=0.f, ndn=0.f;

    __syncthreads();   // weights/bitsM/cntL ready (one-time)

    // ---- interval 0: h1n(0)=0; h0n(1)=GRU(x(bit0),0) ----
    #pragma unroll
    for (int h2=0;h2<2;++h2){
        #pragma unroll
        for (int reg=0;reg<4;++reg){
            int rowL = rw + 4*quad + reg;
            int ucol = j*32 + h2*16 + lm;
            stH(H1 + rowL*HH + ucol, 0.f);
            int bit = (int)(bitsM[rowL] & 1ull);
            float gr = bit?g0w[h2][1]:g0w[h2][0];
            float gz = bit?g0w[h2][3]:g0w[h2][2];
            float gn = bit?g0w[h2][5]:g0w[h2][4];
            float r = sigmoidf_(gr);
            float z = sigmoidf_(gz);
            float n = tanhf_(gn);
            float hnew = (1.f-z)*n;
            hr0[h2][reg] = hnew;
            stH(H0 + (BTC*HH) + rowL*HH + ucol, hnew);
        }
    }
    ARRIVE(0, 0)
    ARRIVE(1, 0)

    // ---- prologue prefetch: A0 for step i=1 (h0n(1) in H0 buffer 1) ----
    half8 A0[8];
    POLL(0, 0)
    {
        const _Float16* Hs0p = H0 + (BTC*HH) + (rw + lm)*HH;
        #pragma unroll
        for (int kt=0;kt<8;++kt) A0[kt] = ldA16(Hs0p + kt*32 + quad*8);
    }

    for (int i=1;i<SS;++i){
        // ================= phase 0: layer-0 recurrence (critical cycle) ====
        WAIT_PIN8("0", A0);   // prefetched at end of previous step (free)

        f32x4 a0n[3][2] = {};                   // [type][h2]
        if (i < SS-1){
            #pragma unroll
            for (int kt=0;kt<8;++kt){
                #pragma unroll
                for (int h2=0;h2<2;++h2){
                    half8 b0r = *(const half8*)(wlds + WOFF(0, 0+h2, kt) + L*8);
                    half8 b0z = *(const half8*)(wlds + WOFF(0, 2+h2, kt) + L*8);
                    half8 b0n = *(const half8*)(wlds + WOFF(0, 4+h2, kt) + L*8);
                    a0n[0][h2] = __builtin_amdgcn_mfma_f32_16x16x32_f16(A0[kt], b0r, a0n[0][h2],0,0,0);
                    a0n[1][h2] = __builtin_amdgcn_mfma_f32_16x16x32_f16(A0[kt], b0z, a0n[1][h2],0,0,0);
                    a0n[2][h2] = __builtin_amdgcn_mfma_f32_16x16x32_f16(A0[kt], b0n, a0n[2][h2],0,0,0);
                }
            }
        }

        // ---- EARLY phase-1 head: poll flag1(i-1), issue hvv + A1 loads ----
        // Their IC round trips hide under ew0 + staging + store below;
        // ARRIVE(0,i)'s vmcnt(0) drains them for free.
        POLL(1, i-1)
        const int s = i-1;
        half8 hvv = ldA16(H1 + (s&1)*(BTC*HH) + srow*HH + cs*8);
        const _Float16* Hs1 = H1 + (s&1)*(BTC*HH) + (rw + lm)*HH;
        half8 A1[8];
        #pragma unroll
        for (int kt=0;kt<8;++kt) A1[kt] = ldA16(Hs1 + kt*32 + quad*8);

        if (i < SS-1){
            // ew0 -> wave-private stage
            #pragma unroll
            for (int h2=0;h2<2;++h2){
                #pragma unroll
                for (int reg=0;reg<4;++reg){
                    int rowL = rw + 4*quad + reg;
                    int bit = (int)((bitsM[rowL] >> i) & 1ull);
                    float gr = bit?g0w[h2][1]:g0w[h2][0];
                    float gz = bit?g0w[h2][3]:g0w[h2][2];
                    float gn = bit?g0w[h2][5]:g0w[h2][4];
                    float r = sigmoidf_(gr + a0n[0][h2][reg]);
                    float z = sigmoidf_(gz + a0n[1][h2][reg]);
                    float n = tanhf_(gn + r*a0n[2][h2][reg]);
                    float hnew = (1.f-z)*n + z*hr0[h2][reg];
                    hr0[h2][reg] = hnew;
                    stg[(4*quad+reg)*32 + h2*16 + lm] = (_Float16)hnew;
                }
            }
            asm volatile("s_waitcnt lgkmcnt(0)" ::: "memory");
            __builtin_amdgcn_sched_barrier(0);
            half8 v = *(const half8*)(stg + r2*32 + q2*8);
            asm volatile("s_waitcnt lgkmcnt(0)" : "+v"(v) :: "memory");
            __builtin_amdgcn_sched_barrier(0);
            stH16(H0 + ((i+1)&1)*(BTC*HH) + (rw + r2)*HH + j*32 + q2*8, v);
            ARRIVE(0, i)    // drains h0n store + hvv + A1 together
        }

        // ================= phase 1: layer-1 + sampling ======================
        // i < SS-1: vmcnt already 0 (ARRIVE0) -> pins are free.
        // i == SS-1: queue = [hvv, A1 x8] -> vmcnt(8)/vmcnt(0) exact.
        asm volatile("s_waitcnt vmcnt(8)" : "+v"(hvv) :: "memory");
        __builtin_amdgcn_sched_barrier(0);
        {
            float s0=0.f, s1=0.f;
            #pragma unroll
            for (int e=0;e<8;++e){ float f=(float)hvv[e]; s0+=f*wl0[e]; s1+=f*wl1[e]; }
            #pragma unroll
            for (int off=16; off>0; off>>=1){ s0+=__shfl_xor(s0,off,32); s1+=__shfl_xor(s1,off,32); }
            float l0=s0+bl0, l1=s1+bl1;
            bool  ev  = (s & 1) == 0;
            float low = -16.f + (float)(s>>1);
            float cnt = ev ? nup : ndn;
            float mocc = (16.f > cnt) ? 1.f : 0.f;
            float mun  = (low  < cnt) ? 1.f : 0.f;
            float mx = fmaxf(l0,l1);
            float e0 = __expf(l0-mx), e1 = __expf(l1-mx);
            float inv = __builtin_amdgcn_rcpf(e0+e1);
            float a0s = __builtin_amdgcn_sqrtf(e0*inv)*mun;
            float a1s = __builtin_amdgcn_sqrtf(e1*inv)*mocc;
            float nrm = __builtin_amdgcn_sqrtf(a0s*a0s + a1s*a1s);
            float den = fmaxf(nrm, 1e-12f);
            float rden = __builtin_amdgcn_rcpf(den);
            a0s*=rden; a1s*=rden;
            const float PI_F = 3.14159265358979323846f;
            float p0 = PI_F*l0*__builtin_amdgcn_rcpf(1.f+fabsf(l0));
            float p1 = PI_F*l1*__builtin_amdgcn_rcpf(1.f+fabsf(l1));
            int bit = (int)((bitsM[srow] >> s) & 1ull);
            amp *= bit ? a1s : a0s;
            ph  += bit ? p1 : p0;
            if (ev) nup += (float)bit; else ndn += (float)bit;
        }

        WAIT_PIN8("0", A1);
        f32x4 aR[2]={}, aZ[2]={}, aNI[2]={}, aNH[2]={};
        #pragma unroll
        for (int kt=0;kt<8;++kt){
            #pragma unroll
            for (int h2=0;h2<2;++h2){
                half8 b1r = *(const half8*)(wlds + WOFF(1, 0+h2, kt) + L*8);
                half8 b1z = *(const half8*)(wlds + WOFF(1, 2+h2, kt) + L*8);
                half8 b1n = *(const half8*)(wlds + WOFF(1, 4+h2, kt) + L*8);
                half8 b2r = *(const half8*)(wlds + WOFF(2, 0+h2, kt) + L*8);
                half8 b2z = *(const half8*)(wlds + WOFF(2, 2+h2, kt) + L*8);
                half8 b2n = *(const half8*)(wlds + WOFF(2, 4+h2, kt) + L*8);
                aR [h2] = __builtin_amdgcn_mfma_f32_16x16x32_f16(A0[kt], b1r, aR [h2],0,0,0);
                aZ [h2] = __builtin_amdgcn_mfma_f32_16x16x32_f16(A0[kt], b1z, aZ [h2],0,0,0);
                aNI[h2] = __builtin_amdgcn_mfma_f32_16x16x32_f16(A0[kt], b1n, aNI[h2],0,0,0);
                aR [h2] = __builtin_amdgcn_mfma_f32_16x16x32_f16(A1[kt], b2r, aR [h2],0,0,0);
                aZ [h2] = __builtin_amdgcn_mfma_f32_16x16x32_f16(A1[kt], b2z, aZ [h2],0,0,0);
                aNH[h2] = __builtin_amdgcn_mfma_f32_16x16x32_f16(A1[kt], b2n, aNH[h2],0,0,0);
            }
        }

        // ew1 -> wave-private stage -> coalesced store
        #pragma unroll
        for (int h2=0;h2<2;++h2){
            #pragma unroll
            for (int reg=0;reg<4;++reg){
                float r = sigmoidf_(aR[h2][reg]);
                float z = sigmoidf_(aZ[h2][reg]);
                float n = tanhf_(aNI[h2][reg] + r*aNH[h2][reg]);
                float hnew = (1.f-z)*n + z*hr1[h2][reg];
                hr1[h2][reg] = hnew;
                stg[(4*quad+reg)*32 + h2*16 + lm] = (_Float16)hnew;
            }
        }
        asm volatile("s_waitcnt lgkmcnt(0)" ::: "memory");
        __builtin_amdgcn_sched_barrier(0);
        {
            half8 v = *(const half8*)(stg + r2*32 + q2*8);
            asm volatile("s_waitcnt lgkmcnt(0)" : "+v"(v) :: "memory");
            __builtin_amdgcn_sched_barrier(0);
            stH16(H1 + (i&1)*(BTC*HH) + (rw + r2)*HH + j*32 + q2*8, v);
        }

        // ---- A0 prefetch for step i+1 (flag0(i) set in steady state) ----
        if (i < SS-1){
            POLL(0, i)
            const _Float16* Hs0n = H0 + ((i+1)&1)*(BTC*HH) + (rw + lm)*HH;
            #pragma unroll
            for (int kt=0;kt<8;++kt) A0[kt] = ldA16(Hs0n + kt*32 + quad*8);
        }

        ARRIVE(1, i)   // drains h1n store + prefetched A0 loads together
    }

    // ---- epilogue: wait flag1(63), sampling(63) ----
    POLL(1, SS-1)
    {
        const int s = SS-1;
        half8 hvv = ldA16(H1 + (s&1)*(BTC*HH) + srow*HH + cs*8);
        asm volatile("s_waitcnt vmcnt(0)" : "+v"(hvv) :: "memory");
        __builtin_amdgcn_sched_barrier(0);
        float s0=0.f, s1=0.f;
        #pragma unroll
        for (int e=0;e<8;++e){ float f=(float)hvv[e]; s0+=f*wl0[e]; s1+=f*wl1[e]; }
        #pragma unroll
        for (int off=16; off>0; off>>=1){ s0+=__shfl_xor(s0,off,32); s1+=__shfl_xor(s1,off,32); }
        float l0=s0+bl0, l1=s1+bl1;
        bool  ev  = (s & 1) == 0;
        float low = -16.f + (float)(s>>1);
        float cnt = ev ? nup : ndn;
        float mocc = (16.f > cnt) ? 1.f : 0.f;
        float mun  = (low  < cnt) ? 1.f : 0.f;
        float mx = fmaxf(l0,l1);
        float e0 = __expf(l0-mx), e1 = __expf(l1-mx);
        float inv = __builtin_amdgcn_rcpf(e0+e1);
        float a0s = __builtin_amdgcn_sqrtf(e0*inv)*mun;
        float a1s = __builtin_amdgcn_sqrtf(e1*inv)*mocc;
        float nrm = __builtin_amdgcn_sqrtf(a0s*a0s + a1s*a1s);
        float den = fmaxf(nrm, 1e-12f);
        float rden = __builtin_amdgcn_rcpf(den);
        a0s*=rden; a1s*=rden;
        const float PI_F = 3.14159265358979323846f;
        float p0 = PI_F*l0*__builtin_amdgcn_rcpf(1.f+fabsf(l0));
        float p1 = PI_F*l1*__builtin_amdgcn_rcpf(1.f+fabsf(l1));
        int bit = (int)((bitsM[srow] >> s) & 1ull);
        amp *= bit ? a1s : a0s;
        ph  += bit ? p1 : p0;
    }
    if (cs == 0) out[c*BTC + srow] = amp * cosf(ph);
}

extern "C" void kernel_launch(void* const* d_in, const int* in_sizes, int n_in,
                              void* d_out, int out_size, void* d_ws, size_t ws_size,
                              hipStream_t stream) {
    (void)in_sizes; (void)n_in; (void)out_size; (void)ws_size;
    const int*   x    = (const int*)d_in[0];
    const float* Wih0 = (const float*)d_in[1];
    const float* Whh0 = (const float*)d_in[2];
    const float* Wih1 = (const float*)d_in[3];
    const float* Whh1 = (const float*)d_in[4];
    const float* Wl   = (const float*)d_in[5];
    const float* bl   = (const float*)d_in[6];

    int*      flags = (int*)d_ws;                          // 32 KB (NCL*SS*2*8 bytes)
    _Float16* Hbuf  = (_Float16*)((char*)d_ws + 131072);   // 8 MB h state

    zero_flags<<<(NCL*SS*4 + 255)/256, 256, 0, stream>>>(flags);
    rnn_cluster<<<NCL*CW, NT, 0, stream>>>(x, Wih0, Whh0, Wih1, Whh1, Wl, bl,
                                           (float*)d_out, flags, Hbuf);
}